// Round 5
// baseline (430.048 us; speedup 1.0000x reference)
//
#include <hip/hip_runtime.h>
#include <math.h>

#define GROUPS 2
#define NVARS  320
#define VDIM   128
#define NCOLS  640
#define FSZ    768
#define BTOT   32768
#define QDIM   256
#define KT     24        // 768/32 k-tiles
#define GAPTH  0.05f
#define LISTCAP 131072

typedef __bf16 bf16x8 __attribute__((ext_vector_type(8)));
typedef float  f32x4  __attribute__((ext_vector_type(4)));

// ---------------- helpers ----------------
__device__ __forceinline__ void gl_lds16(const void* g, void* l) {
    __builtin_amdgcn_global_load_lds(
        (const __attribute__((address_space(1))) unsigned int*)g,
        (__attribute__((address_space(3))) unsigned int*)l, 16, 0, 0);
}

// ---------------- x pre-pass: f32 -> tile-linear bf16 hi/lo ----------------
__global__ __launch_bounds__(128) void xpre(
    const float* __restrict__ x, __bf16* __restrict__ xh, __bf16* __restrict__ xl, int row0)
{
    const int b = blockIdx.x;
    const int mblk = b / KT, kblk = b % KT;
    const int m = threadIdx.x;
    const float* src = x + (size_t)(row0 + mblk*128 + m) * FSZ + kblk*32;
    const size_t tbase = ((size_t)mblk*KT + kblk) * 4096;
    #pragma unroll
    for (int kq = 0; kq < 4; ++kq) {
        float4 a = ((const float4*)src)[kq*2];
        float4 c = ((const float4*)src)[kq*2+1];
        float vv[8] = {a.x,a.y,a.z,a.w,c.x,c.y,c.z,c.w};
        bf16x8 h, l;
        #pragma unroll
        for (int j = 0; j < 8; ++j) {
            __bf16 hh = (__bf16)vv[j];
            h[j] = hh;
            l[j] = (__bf16)(vv[j] - (float)hh);
        }
        ((bf16x8*)(xh + tbase))[kq*128 + m] = h;
        ((bf16x8*)(xl + tbase))[kq*128 + m] = l;
    }
}

// ---------------- W pre-pass (runs once; W is 2MB) ----------------
__global__ __launch_bounds__(128) void wpre(
    const float* __restrict__ W, __bf16* __restrict__ wh, __bf16* __restrict__ wl)
{
    const int b = blockIdx.x;
    const int nblk = b / KT, kblk = b % KT;
    const int n = threadIdx.x;
    const size_t tbase = ((size_t)nblk*KT + kblk) * 4096;
    #pragma unroll
    for (int kq = 0; kq < 4; ++kq) {
        bf16x8 h, l;
        #pragma unroll
        for (int j = 0; j < 8; ++j) {
            float v = W[(size_t)(kblk*32 + kq*8 + j) * NCOLS + nblk*128 + n];
            __bf16 hh = (__bf16)v;
            h[j] = hh;
            l[j] = (__bf16)(v - (float)hh);
        }
        ((bf16x8*)(wh + tbase))[kq*128 + n] = h;
        ((bf16x8*)(wl + tbase))[kq*128 + n] = l;
    }
}

// ---------------- MFMA GEMM: logits = x@W + b via bf16x3 ----------------
__global__ __launch_bounds__(256) void gemm_mfma(
    const __bf16* __restrict__ xh, const __bf16* __restrict__ xl,
    const __bf16* __restrict__ wh, const __bf16* __restrict__ wl,
    const float* __restrict__ bias, float* __restrict__ logits, int nwg)
{
    __shared__ __bf16 lds[16384];   // AH | AL | BH | BL, 4096 bf16 each (32 KB)

    const int b = blockIdx.x;
    const int q8 = nwg >> 3, r8 = nwg & 7;
    const int xcd = b & 7, pos = b >> 3;
    const int L = (xcd < r8 ? xcd*(q8+1) : r8*(q8+1) + (xcd - r8)*q8) + pos;
    const int mblk = L / 5, nblk = L % 5;

    const int tid = threadIdx.x;
    const int w = tid >> 6, lane = tid & 63;
    const int wr = w >> 1, wc = w & 1;
    const int qq = lane >> 4, rr = lane & 15;

    f32x4 acc[4][4];
    #pragma unroll
    for (int i = 0; i < 4; ++i)
        #pragma unroll
        for (int j = 0; j < 4; ++j) acc[i][j] = (f32x4)0.f;

    const int ab = qq*128 + wr*64 + rr;
    const int bb = qq*128 + wc*64 + rr;

    for (int kt = 0; kt < KT; ++kt) {
        __syncthreads();
        const __bf16* ah_s = xh + ((size_t)mblk*KT + kt)*4096;
        const __bf16* al_s = xl + ((size_t)mblk*KT + kt)*4096;
        const __bf16* bh_s = wh + ((size_t)nblk*KT + kt)*4096;
        const __bf16* bl_s = wl + ((size_t)nblk*KT + kt)*4096;
        #pragma unroll
        for (int i = 0; i < 2; ++i) {
            const int u  = w*128 + i*64;
            const int el = (u + lane)*8;
            const int ed = u*8;
            gl_lds16(ah_s + el, &lds[0     + ed]);
            gl_lds16(al_s + el, &lds[4096  + ed]);
            gl_lds16(bh_s + el, &lds[8192  + ed]);
            gl_lds16(bl_s + el, &lds[12288 + ed]);
        }
        __syncthreads();

        const bf16x8* LAH = (const bf16x8*)&lds[0];
        const bf16x8* LAL = (const bf16x8*)&lds[4096];
        const bf16x8* LBH = (const bf16x8*)&lds[8192];
        const bf16x8* LBL = (const bf16x8*)&lds[12288];
        bf16x8 ah[4], al[4], bh[4], bl[4];
        #pragma unroll
        for (int mf = 0; mf < 4; ++mf) { ah[mf] = LAH[ab + mf*16]; al[mf] = LAL[ab + mf*16]; }
        #pragma unroll
        for (int nf = 0; nf < 4; ++nf) { bh[nf] = LBH[bb + nf*16]; bl[nf] = LBL[bb + nf*16]; }

        #pragma unroll
        for (int mf = 0; mf < 4; ++mf)
            #pragma unroll
            for (int nf = 0; nf < 4; ++nf) {
                acc[mf][nf] = __builtin_amdgcn_mfma_f32_16x16x32_bf16(ah[mf], bh[nf], acc[mf][nf], 0, 0, 0);
                acc[mf][nf] = __builtin_amdgcn_mfma_f32_16x16x32_bf16(al[mf], bh[nf], acc[mf][nf], 0, 0, 0);
                acc[mf][nf] = __builtin_amdgcn_mfma_f32_16x16x32_bf16(ah[mf], bl[nf], acc[mf][nf], 0, 0, 0);
            }
    }

    const int row0b = mblk*128 + wr*64;
    const int col0  = nblk*128 + wc*64;
    #pragma unroll
    for (int nf = 0; nf < 4; ++nf) {
        const int col = col0 + nf*16 + rr;
        const float bv = bias[col];
        #pragma unroll
        for (int mf = 0; mf < 4; ++mf) {
            const int rowb = row0b + mf*16 + qq*4;
            #pragma unroll
            for (int j = 0; j < 4; ++j)
                logits[(size_t)(rowb + j)*NCOLS + col] = acc[mf][nf][j] + bv;
        }
    }
}

// ---------------- rows: argmax + gap-flag + softmax partials + gather ----------------
#define RPB 16
__global__ __launch_bounds__(256) void rows_kernel(
    const float* __restrict__ logits, const float* __restrict__ cb,
    float* __restrict__ qout, float* __restrict__ partials,
    int* __restrict__ counter, int* __restrict__ list, int row0)
{
    __shared__ float probacc[4][NCOLS];
    const int tid = threadIdx.x, wid = tid >> 6, lane = tid & 63;
    for (int c = tid; c < 4*NCOLS; c += 256) ((float*)probacc)[c] = 0.f;
    __syncthreads();

    #pragma unroll
    for (int i = 0; i < RPB/4; ++i) {
        const int rl = blockIdx.x*RPB + wid*(RPB/4) + i;
        const float* lr = logits + (size_t)rl*NCOLS;
        const size_t grow = (size_t)row0 + rl;
        #pragma unroll
        for (int g = 0; g < GROUPS; ++g) {
            float v[5];
            #pragma unroll
            for (int j = 0; j < 5; ++j) v[j] = lr[g*NVARS + lane + 64*j];
            float m = v[0], m2 = -3.4e38f; int idx = lane;
            #pragma unroll
            for (int j = 1; j < 5; ++j) {
                if (v[j] > m) { m2 = m; m = v[j]; idx = lane + 64*j; }
                else m2 = fmaxf(m2, v[j]);
            }
            #pragma unroll
            for (int off = 32; off > 0; off >>= 1) {
                float om  = __shfl_xor(m, off);
                int   oi  = __shfl_xor(idx, off);
                float om2 = __shfl_xor(m2, off);
                if (om > m || (om == m && oi < idx)) { m2 = fmaxf(m, om2); m = om; idx = oi; }
                else m2 = fmaxf(m2, om);
            }
            float e[5], s = 0.f;
            #pragma unroll
            for (int j = 0; j < 5; ++j) { e[j] = __expf(v[j] - m); s += e[j]; }
            #pragma unroll
            for (int off = 32; off > 0; off >>= 1) s += __shfl_xor(s, off);
            const float inv = 1.0f / s;
            #pragma unroll
            for (int j = 0; j < 5; ++j)
                probacc[wid][g*NVARS + lane + 64*j] += e[j] * inv;
            if (lane == 0 && (m - m2) < GAPTH) {
                int p = atomicAdd(counter, 1);
                if (p < LISTCAP) list[p] = ((int)grow << 1) | g;
            }
            const float2* srcc = (const float2*)(cb + (size_t)(g*NVARS + idx)*VDIM);
            float2* dst = (float2*)(qout + grow*QDIM + (size_t)g*VDIM);
            dst[lane] = srcc[lane];
        }
    }
    __syncthreads();
    const size_t pb = (size_t)(row0 >> 4) + blockIdx.x;
    for (int c = tid; c < NCOLS; c += 256)
        partials[pb*NCOLS + c] = probacc[0][c] + probacc[1][c] + probacc[2][c] + probacc[3][c];
}

// ---------------- fixup v3: 4 waves split K, 8-wide unroll, LDS reduce ----------------
__global__ __launch_bounds__(256) void fixup_kernel(
    const float* __restrict__ x, const float* __restrict__ W,
    const float* __restrict__ bias, const float* __restrict__ cb,
    float* __restrict__ qout, const int* __restrict__ counter, const int* __restrict__ list)
{
    __shared__ float red[4][NVARS];    // per-wave partial logits
    int cnt = *counter; if (cnt > LISTCAP) cnt = LISTCAP;
    const int tid = threadIdx.x, w = tid >> 6, lane = tid & 63;

    for (int e = blockIdx.x; e < cnt; e += gridDim.x) {
        const int ent = list[e];
        const int row = ent >> 1, g = ent & 1;
        const float* xr = x + (size_t)row*FSZ;

        float acc[5] = {0.f, 0.f, 0.f, 0.f, 0.f};
        // wave w covers k in [w*192, w*192+192); 8-wide unroll -> 40 indep FMAs/iter
        for (int k0 = w*192; k0 < w*192 + 192; k0 += 8) {
            const float4 xv0 = *(const float4*)(xr + k0);
            const float4 xv1 = *(const float4*)(xr + k0 + 4);
            const float xs[8] = {xv0.x, xv0.y, xv0.z, xv0.w, xv1.x, xv1.y, xv1.z, xv1.w};
            #pragma unroll
            for (int kk = 0; kk < 8; ++kk) {
                const float* wrow = W + (size_t)(k0 + kk)*NCOLS + g*NVARS;
                #pragma unroll
                for (int j = 0; j < 5; ++j)
                    acc[j] = fmaf(xs[kk], wrow[lane + 64*j], acc[j]);
            }
        }
        __syncthreads();   // previous iteration's red reads done
        #pragma unroll
        for (int j = 0; j < 5; ++j) red[w][lane + 64*j] = acc[j];
        __syncthreads();

        // all waves redundantly reduce + argmax (uniform result)
        float v[5];
        #pragma unroll
        for (int j = 0; j < 5; ++j) {
            const int c = lane + 64*j;
            v[j] = red[0][c] + red[1][c] + red[2][c] + red[3][c] + bias[g*NVARS + c];
        }
        float m = v[0]; int idx = lane;
        #pragma unroll
        for (int j = 1; j < 5; ++j) if (v[j] > m) { m = v[j]; idx = lane + 64*j; }
        #pragma unroll
        for (int off = 32; off > 0; off >>= 1) {
            float om = __shfl_xor(m, off);
            int   oi = __shfl_xor(idx, off);
            if (om > m || (om == m && oi < idx)) { m = om; idx = oi; }
        }
        if (w == 0) {
            const float2* srcc = (const float2*)(cb + (size_t)(g*NVARS + idx)*VDIM);
            float2* dst = (float2*)(qout + (size_t)row*QDIM + (size_t)g*VDIM);
            dst[lane] = srcc[lane];
        }
    }
}

// ---------------- reduce v2: coalesced p-stripe sweep + atomicAdd into avg ----------------
#define REDBLK 16
__global__ __launch_bounds__(256) void reduce_kernel(
    const float* __restrict__ partials, float* __restrict__ avg)
{
    const int tid = threadIdx.x;
    const int p0 = blockIdx.x * (BTOT/RPB/REDBLK);   // 128 p-rows per block
    float s[3] = {0.f, 0.f, 0.f};
    for (int p = p0; p < p0 + BTOT/RPB/REDBLK; ++p) {
        const float* row = partials + (size_t)p*NCOLS;
        #pragma unroll
        for (int i = 0; i < 3; ++i) {
            const int c = tid + i*256;
            if (c < NCOLS) s[i] += row[c];
        }
    }
    #pragma unroll
    for (int i = 0; i < 3; ++i) {
        const int c = tid + i*256;
        if (c < NCOLS) atomicAdd(&avg[c], s[i]);
    }
}

// ---------------- finalize: ppl + temp ----------------
__global__ __launch_bounds__(64) void finalize_kernel(
    const float* __restrict__ avg, float* __restrict__ out)
{
    const int lane = threadIdx.x;
    float pp[GROUPS];
    #pragma unroll
    for (int g = 0; g < GROUPS; ++g) {
        float s = 0.f;
        #pragma unroll
        for (int j = 0; j < 5; ++j) {
            float p = avg[g*NVARS + lane + 64*j] * (1.0f/(float)BTOT);
            s += p * logf(p + 1e-7f);
        }
        #pragma unroll
        for (int off = 32; off > 0; off >>= 1) s += __shfl_xor(s, off);
        pp[g] = expf(-s);
    }
    if (lane == 0) {
        float ppl = pp[0] + pp[1];
        out[(size_t)BTOT*QDIM]     = ((float)NCOLS - ppl) / (float)NCOLS;
        out[(size_t)BTOT*QDIM + 1] = 2.0f;
    }
}

// ---------------- launcher ----------------
extern "C" void kernel_launch(void* const* d_in, const int* in_sizes, int n_in,
                              void* d_out, int out_size, void* d_ws, size_t ws_size,
                              hipStream_t stream)
{
    const float* x  = (const float*)d_in[0];
    const float* W  = (const float*)d_in[1];
    const float* b  = (const float*)d_in[2];
    const float* cb = (const float*)d_in[3];
    float* out = (float*)d_out;

    char* ws = (char*)d_ws;
    int*   counter  = (int*)ws;                 // [0,4)
    float* avg      = (float*)(ws + 1024);      // [1024, 3584) -- zeroed by memset below
    int*   list     = (int*)(ws + 8192);
    float* partials = (float*)(ws + 532480);
    __bf16* wh      = (__bf16*)(ws + 5775360);
    __bf16* wl      = (__bf16*)(ws + 6758400);
    char* chunkbase = ws + 7741440;

    // even-split, 128-aligned chunking (balanced loads across chunks)
    long long avail = (long long)ws_size - 7741440;
    long long rmax = avail / 5632;              // per-row: xh+xl 3072B + logits 2560B
    if (rmax > BTOT) rmax = BTOT;
    if (rmax < 128)  rmax = 128;
    int chunks = (int)((BTOT + rmax - 1) / rmax);
    int R = ((BTOT / chunks + 127) / 128) * 128;

    hipMemsetAsync(ws, 0, 4096, stream);        // counter + avg
    wpre<<<5*KT, 128, 0, stream>>>(W, wh, wl);

    for (int row0 = 0; row0 < BTOT; row0 += R) {
        int Rc = BTOT - row0; if (Rc > R) Rc = R;
        const int nmb = Rc / 128;
        __bf16* xh = (__bf16*)chunkbase;
        __bf16* xl = xh + (size_t)nmb*KT*4096;
        float* logits = (float*)(xl + (size_t)nmb*KT*4096);

        xpre<<<nmb*KT, 128, 0, stream>>>(x, xh, xl, row0);
        const int nwg = nmb * 5;
        gemm_mfma<<<nwg, 256, 0, stream>>>(xh, xl, wh, wl, b, logits, nwg);
        rows_kernel<<<Rc/RPB, 256, 0, stream>>>(logits, cb, out, partials, counter, list, row0);
    }
    fixup_kernel<<<512, 256, 0, stream>>>(x, W, b, cb, out, counter, list);
    reduce_kernel<<<REDBLK, 256, 0, stream>>>(partials, avg);
    finalize_kernel<<<1, 64, 0, stream>>>(avg, out);
}

// Round 6
// 391.155 us; speedup vs baseline: 1.0994x; 1.0994x over previous
//
#include <hip/hip_runtime.h>
#include <math.h>

#define GROUPS 2
#define NVARS  320
#define VDIM   128
#define NCOLS  640
#define FSZ    768
#define BTOT   32768
#define QDIM   256
#define KT     24        // 768/32 k-tiles
#define GAPTH  0.05f
#define LISTCAP 131072

typedef __bf16 bf16x8 __attribute__((ext_vector_type(8)));
typedef __bf16 bf16x4 __attribute__((ext_vector_type(4)));
typedef float  f32x4  __attribute__((ext_vector_type(4)));

// ---------------- helpers ----------------
__device__ __forceinline__ void gl_lds16(const void* g, void* l) {
    __builtin_amdgcn_global_load_lds(
        (const __attribute__((address_space(1))) unsigned int*)g,
        (__attribute__((address_space(3))) unsigned int*)l, 16, 0, 0);
}

// ---------------- W pre-pass (runs once; W is 2MB) ----------------
// tile (nblk,kblk): unit u = kq*128 + n holds W[kblk*32+kq*8+j][nblk*128+n]
__global__ __launch_bounds__(128) void wpre(
    const float* __restrict__ W, __bf16* __restrict__ wh, __bf16* __restrict__ wl)
{
    const int b = blockIdx.x;
    const int nblk = b / KT, kblk = b % KT;
    const int n = threadIdx.x;
    const size_t tbase = ((size_t)nblk*KT + kblk) * 4096;
    #pragma unroll
    for (int kq = 0; kq < 4; ++kq) {
        bf16x8 h, l;
        #pragma unroll
        for (int j = 0; j < 8; ++j) {
            float v = W[(size_t)(kblk*32 + kq*8 + j) * NCOLS + nblk*128 + n];
            __bf16 hh = (__bf16)v;
            h[j] = hh;
            l[j] = (__bf16)(v - (float)hh);
        }
        ((bf16x8*)(wh + tbase))[kq*128 + n] = h;
        ((bf16x8*)(wl + tbase))[kq*128 + n] = l;
    }
}

// ---------------- fused MFMA GEMM: logits = x @ W + b via bf16x3 ----------------
// A-staging fused: load x f32 directly, split to bf16 hi/lo in-register, ds_write.
// LDS: AH[0,4096) AL[4096,8192) BH[8192,12288) BL[12288,16384) bf16 elems.
__global__ __launch_bounds__(256, 4) void gemm_fused(
    const float* __restrict__ x,
    const __bf16* __restrict__ wh, const __bf16* __restrict__ wl,
    const float* __restrict__ bias, float* __restrict__ logits, int nwg, int row0)
{
    __shared__ __bf16 lds[16384];   // 32 KB

    // bijective XCD swizzle, n-fastest (same-m blocks share an XCD L2)
    const int b = blockIdx.x;
    const int q8 = nwg >> 3, r8 = nwg & 7;
    const int xcd = b & 7, pos = b >> 3;
    const int L = (xcd < r8 ? xcd*(q8+1) : r8*(q8+1) + (xcd - r8)*q8) + pos;
    const int mblk = L / 5, nblk = L % 5;

    const int tid = threadIdx.x;
    const int w = tid >> 6, lane = tid & 63;
    const int wr = w >> 1, wc = w & 1;
    const int qq = lane >> 4, rr = lane & 15;

    f32x4 acc[4][4];
    #pragma unroll
    for (int i = 0; i < 4; ++i)
        #pragma unroll
        for (int j = 0; j < 4; ++j) acc[i][j] = (f32x4)0.f;

    const int ab = qq*128 + wr*64 + rr;   // A frag unit index
    const int bb = qq*128 + wc*64 + rr;   // B frag unit index

    // A-staging thread mapping: 4 rounds x (32 rows x 8 col-quads)
    const int prow = tid >> 3;            // 0..31
    const int pc   = tid & 7;             // col-quad 0..7 (4 floats each)
    const float* xbase = x + (size_t)(row0 + mblk*128 + prow) * FSZ + pc*4;
    const int aelem = ((pc >> 1)*128)*8 + (pc & 1)*4 + prow*8;  // + r*32*8 per round

    // prefetch x for kt=0 (4 float4 = 16 VGPR)
    float4 xv0 = *(const float4*)(xbase);
    float4 xv1 = *(const float4*)(xbase + 32*FSZ);
    float4 xv2 = *(const float4*)(xbase + 64*FSZ);
    float4 xv3 = *(const float4*)(xbase + 96*FSZ);

    for (int kt = 0; kt < KT; ++kt) {
        __syncthreads();                                   // LDS free to overwrite
        // --- stage A: convert hi/lo + ds_write (2-way bank = free) ---
        {
            float4 xr[4] = {xv0, xv1, xv2, xv3};
            #pragma unroll
            for (int r = 0; r < 4; ++r) {
                const float vv[4] = {xr[r].x, xr[r].y, xr[r].z, xr[r].w};
                bf16x4 h, l;
                #pragma unroll
                for (int j = 0; j < 4; ++j) {
                    __bf16 hh = (__bf16)vv[j];
                    h[j] = hh;
                    l[j] = (__bf16)(vv[j] - (float)hh);
                }
                const int e = aelem + r*256;               // r*32 rows * 8 elems
                *(bf16x4*)&lds[e]        = h;
                *(bf16x4*)&lds[4096 + e] = l;
            }
        }
        // --- stage B: async global->LDS ---
        const __bf16* bh_s = wh + ((size_t)nblk*KT + kt)*4096;
        const __bf16* bl_s = wl + ((size_t)nblk*KT + kt)*4096;
        #pragma unroll
        for (int i = 0; i < 2; ++i) {
            const int u = w*128 + i*64;
            gl_lds16(bh_s + (u + lane)*8, &lds[8192  + u*8]);
            gl_lds16(bl_s + (u + lane)*8, &lds[12288 + u*8]);
        }
        __syncthreads();                                   // staged data ready

        // prefetch x for next tile (hides under MFMA + co-resident waves)
        {
            const int ktn = (kt + 1 < KT) ? kt + 1 : kt;
            const float* xp = xbase + ktn*32;
            xv0 = *(const float4*)(xp);
            xv1 = *(const float4*)(xp + 32*FSZ);
            xv2 = *(const float4*)(xp + 64*FSZ);
            xv3 = *(const float4*)(xp + 96*FSZ);
        }

        const bf16x8* LAH = (const bf16x8*)&lds[0];
        const bf16x8* LAL = (const bf16x8*)&lds[4096];
        const bf16x8* LBH = (const bf16x8*)&lds[8192];
        const bf16x8* LBL = (const bf16x8*)&lds[12288];
        bf16x8 ah[4], al[4], bh[4], bl[4];
        #pragma unroll
        for (int mf = 0; mf < 4; ++mf) { ah[mf] = LAH[ab + mf*16]; al[mf] = LAL[ab + mf*16]; }
        #pragma unroll
        for (int nf = 0; nf < 4; ++nf) { bh[nf] = LBH[bb + nf*16]; bl[nf] = LBL[bb + nf*16]; }

        #pragma unroll
        for (int mf = 0; mf < 4; ++mf)
            #pragma unroll
            for (int nf = 0; nf < 4; ++nf) {
                acc[mf][nf] = __builtin_amdgcn_mfma_f32_16x16x32_bf16(ah[mf], bh[nf], acc[mf][nf], 0, 0, 0);
                acc[mf][nf] = __builtin_amdgcn_mfma_f32_16x16x32_bf16(al[mf], bh[nf], acc[mf][nf], 0, 0, 0);
                acc[mf][nf] = __builtin_amdgcn_mfma_f32_16x16x32_bf16(ah[mf], bl[nf], acc[mf][nf], 0, 0, 0);
            }
    }

    // epilogue: C/D layout col=lane&15, row=(lane>>4)*4+j  [verified m89/m91]
    const int row0b = mblk*128 + wr*64;
    const int col0  = nblk*128 + wc*64;
    #pragma unroll
    for (int nf = 0; nf < 4; ++nf) {
        const int col = col0 + nf*16 + rr;
        const float bv = bias[col];
        #pragma unroll
        for (int mf = 0; mf < 4; ++mf) {
            const int rowb = row0b + mf*16 + qq*4;
            #pragma unroll
            for (int j = 0; j < 4; ++j)
                logits[(size_t)(rowb + j)*NCOLS + col] = acc[mf][nf][j] + bv;
        }
    }
}

// ---------------- rows: argmax + gap-flag + softmax partials + gather ----------------
#define RPB 16
__global__ __launch_bounds__(256) void rows_kernel(
    const float* __restrict__ logits, const float* __restrict__ cb,
    float* __restrict__ qout, float* __restrict__ partials,
    int* __restrict__ counter, int* __restrict__ list, int row0)
{
    __shared__ float probacc[4][NCOLS];
    const int tid = threadIdx.x, wid = tid >> 6, lane = tid & 63;
    for (int c = tid; c < 4*NCOLS; c += 256) ((float*)probacc)[c] = 0.f;
    __syncthreads();

    #pragma unroll
    for (int i = 0; i < RPB/4; ++i) {
        const int rl = blockIdx.x*RPB + wid*(RPB/4) + i;
        const float* lr = logits + (size_t)rl*NCOLS;
        const size_t grow = (size_t)row0 + rl;
        #pragma unroll
        for (int g = 0; g < GROUPS; ++g) {
            float v[5];
            #pragma unroll
            for (int j = 0; j < 5; ++j) v[j] = lr[g*NVARS + lane + 64*j];
            float m = v[0], m2 = -3.4e38f; int idx = lane;
            #pragma unroll
            for (int j = 1; j < 5; ++j) {
                if (v[j] > m) { m2 = m; m = v[j]; idx = lane + 64*j; }
                else m2 = fmaxf(m2, v[j]);
            }
            #pragma unroll
            for (int off = 32; off > 0; off >>= 1) {
                float om  = __shfl_xor(m, off);
                int   oi  = __shfl_xor(idx, off);
                float om2 = __shfl_xor(m2, off);
                if (om > m || (om == m && oi < idx)) { m2 = fmaxf(m, om2); m = om; idx = oi; }
                else m2 = fmaxf(m2, om);
            }
            float e[5], s = 0.f;
            #pragma unroll
            for (int j = 0; j < 5; ++j) { e[j] = __expf(v[j] - m); s += e[j]; }
            #pragma unroll
            for (int off = 32; off > 0; off >>= 1) s += __shfl_xor(s, off);
            const float inv = 1.0f / s;
            #pragma unroll
            for (int j = 0; j < 5; ++j)
                probacc[wid][g*NVARS + lane + 64*j] += e[j] * inv;
            if (lane == 0 && (m - m2) < GAPTH) {
                int p = atomicAdd(counter, 1);
                if (p < LISTCAP) list[p] = ((int)grow << 1) | g;
            }
            const float2* srcc = (const float2*)(cb + (size_t)(g*NVARS + idx)*VDIM);
            float2* dst = (float2*)(qout + grow*QDIM + (size_t)g*VDIM);
            dst[lane] = srcc[lane];
        }
    }
    __syncthreads();
    const size_t pb = (size_t)(row0 >> 4) + blockIdx.x;
    for (int c = tid; c < NCOLS; c += 256)
        partials[pb*NCOLS + c] = probacc[0][c] + probacc[1][c] + probacc[2][c] + probacc[3][c];
}

// ---------------- fixup: exact fp32 recompute of near-tie row-groups ----------------
__global__ __launch_bounds__(256) void fixup_kernel(
    const float* __restrict__ x, const float* __restrict__ W,
    const float* __restrict__ bias, const float* __restrict__ cb,
    float* __restrict__ qout, const int* __restrict__ counter, const int* __restrict__ list)
{
    __shared__ float red[4][NVARS];
    int cnt = *counter; if (cnt > LISTCAP) cnt = LISTCAP;
    const int tid = threadIdx.x, w = tid >> 6, lane = tid & 63;

    for (int e = blockIdx.x; e < cnt; e += gridDim.x) {
        const int ent = list[e];
        const int row = ent >> 1, g = ent & 1;
        const float* xr = x + (size_t)row*FSZ;

        float acc[5] = {0.f, 0.f, 0.f, 0.f, 0.f};
        for (int k0 = w*192; k0 < w*192 + 192; k0 += 8) {
            const float4 xva = *(const float4*)(xr + k0);
            const float4 xvb = *(const float4*)(xr + k0 + 4);
            const float xs[8] = {xva.x, xva.y, xva.z, xva.w, xvb.x, xvb.y, xvb.z, xvb.w};
            #pragma unroll
            for (int kk = 0; kk < 8; ++kk) {
                const float* wrow = W + (size_t)(k0 + kk)*NCOLS + g*NVARS;
                #pragma unroll
                for (int j = 0; j < 5; ++j)
                    acc[j] = fmaf(xs[kk], wrow[lane + 64*j], acc[j]);
            }
        }
        __syncthreads();
        #pragma unroll
        for (int j = 0; j < 5; ++j) red[w][lane + 64*j] = acc[j];
        __syncthreads();

        float v[5];
        #pragma unroll
        for (int j = 0; j < 5; ++j) {
            const int c = lane + 64*j;
            v[j] = red[0][c] + red[1][c] + red[2][c] + red[3][c] + bias[g*NVARS + c];
        }
        float m = v[0]; int idx = lane;
        #pragma unroll
        for (int j = 1; j < 5; ++j) if (v[j] > m) { m = v[j]; idx = lane + 64*j; }
        #pragma unroll
        for (int off = 32; off > 0; off >>= 1) {
            float om = __shfl_xor(m, off);
            int   oi = __shfl_xor(idx, off);
            if (om > m || (om == m && oi < idx)) { m = om; idx = oi; }
        }
        if (w == 0) {
            const float2* srcc = (const float2*)(cb + (size_t)(g*NVARS + idx)*VDIM);
            float2* dst = (float2*)(qout + (size_t)row*QDIM + (size_t)g*VDIM);
            dst[lane] = srcc[lane];
        }
    }
}

// ---------------- reduce: coalesced p-stripe sweep + atomicAdd into avg ----------------
#define REDBLK 16
__global__ __launch_bounds__(256) void reduce_kernel(
    const float* __restrict__ partials, float* __restrict__ avg)
{
    const int tid = threadIdx.x;
    const int p0 = blockIdx.x * (BTOT/RPB/REDBLK);
    float s[3] = {0.f, 0.f, 0.f};
    for (int p = p0; p < p0 + BTOT/RPB/REDBLK; ++p) {
        const float* row = partials + (size_t)p*NCOLS;
        #pragma unroll
        for (int i = 0; i < 3; ++i) {
            const int c = tid + i*256;
            if (c < NCOLS) s[i] += row[c];
        }
    }
    #pragma unroll
    for (int i = 0; i < 3; ++i) {
        const int c = tid + i*256;
        if (c < NCOLS) atomicAdd(&avg[c], s[i]);
    }
}

// ---------------- finalize: ppl + temp ----------------
__global__ __launch_bounds__(64) void finalize_kernel(
    const float* __restrict__ avg, float* __restrict__ out)
{
    const int lane = threadIdx.x;
    float pp[GROUPS];
    #pragma unroll
    for (int g = 0; g < GROUPS; ++g) {
        float s = 0.f;
        #pragma unroll
        for (int j = 0; j < 5; ++j) {
            float p = avg[g*NVARS + lane + 64*j] * (1.0f/(float)BTOT);
            s += p * logf(p + 1e-7f);
        }
        #pragma unroll
        for (int off = 32; off > 0; off >>= 1) s += __shfl_xor(s, off);
        pp[g] = expf(-s);
    }
    if (lane == 0) {
        float ppl = pp[0] + pp[1];
        out[(size_t)BTOT*QDIM]     = ((float)NCOLS - ppl) / (float)NCOLS;
        out[(size_t)BTOT*QDIM + 1] = 2.0f;
    }
}

// ---------------- launcher ----------------
extern "C" void kernel_launch(void* const* d_in, const int* in_sizes, int n_in,
                              void* d_out, int out_size, void* d_ws, size_t ws_size,
                              hipStream_t stream)
{
    const float* x  = (const float*)d_in[0];
    const float* W  = (const float*)d_in[1];
    const float* b  = (const float*)d_in[2];
    const float* cb = (const float*)d_in[3];
    float* out = (float*)d_out;

    char* ws = (char*)d_ws;
    int*   counter  = (int*)ws;                 // [0,4)
    float* avg      = (float*)(ws + 1024);      // [1024,3584), zeroed below
    int*   list     = (int*)(ws + 8192);        // 512 KB
    float* partials = (float*)(ws + 532480);    // 2048*640*4 = 5 MB
    __bf16* wh      = (__bf16*)(ws + 5775360);  // 960 KB
    __bf16* wl      = (__bf16*)(ws + 6758400);  // 960 KB
    float* logits   = (float*)(ws + 7741440);   // per-row 2560 B -> 84 MB full

    // greedy chunking; with per-row cost 2560 B a single chunk needs ~92 MB total,
    // which fits the (>=100 MB, evidenced by rounds 4/5) workspace -> chunks == 1.
    long long avail = (long long)ws_size - 7741440;
    long long rmax = avail / 2560;
    if (rmax > BTOT) rmax = BTOT;
    int R = (int)((rmax / 128) * 128);
    if (R < 128) R = 128;

    hipMemsetAsync(ws, 0, 4096, stream);        // counter + avg
    wpre<<<5*KT, 128, 0, stream>>>(W, wh, wl);

    for (int row0 = 0; row0 < BTOT; row0 += R) {
        int Rc = BTOT - row0; if (Rc > R) Rc = R;
        const int nmb = Rc / 128;
        const int nwg = nmb * 5;
        gemm_fused<<<nwg, 256, 0, stream>>>(x, wh, wl, b, logits, nwg, row0);
        rows_kernel<<<Rc/RPB, 256, 0, stream>>>(logits, cb, out, partials, counter, list, row0);
    }
    fixup_kernel<<<512, 256, 0, stream>>>(x, W, b, cb, out, counter, list);
    reduce_kernel<<<REDBLK, 256, 0, stream>>>(partials, avg);
    finalize_kernel<<<1, 64, 0, stream>>>(avg, out);
}